// Round 11
// baseline (580.561 us; speedup 1.0000x reference)
//
#include <hip/hip_runtime.h>
#include <hip/hip_bf16.h>
#include <cstdint>

// TGAT fused pipeline for MI355X — round 11: r8 k3 skeleton + project-before-
// scatter backend (6 scalars/edge, per-head denominators, private 64B rows).
//   k1: h1pre = x @ Wlin + blin  via mfma_16x16x32_f16
//   k2: encoders per-thread; comb + Q/K/V/skip as block MFMAs; skip projected
//       onto Wout in-kernel -> skip2 (f32x2/node)
//   k3: edge kernel — r8 gather/MFMA/p-reduce; tail projects message onto
//       Wout, 16-lane reduce, 3 pk-bf16 atomics into acc[dst][32] (one line)
//   k4: out = log_softmax(Y0./den0 + Y1./den1 + skip2 + bout)

#define FIN 172
#define INV_SQRT_C 0.25f

typedef _Float16 f16x8 __attribute__((ext_vector_type(8)));
typedef float f32x4 __attribute__((ext_vector_type(4)));

__device__ __forceinline__ uint32_t cvt_pk_bf16(float lo, float hi) {
    uint32_t r;
    asm("v_cvt_pk_bf16_f32 %0, %1, %2" : "=v"(r) : "v"(lo), "v"(hi));
    return r;
}
__device__ __forceinline__ float bflo(uint32_t u) {
    union { uint32_t i; float f; } x; x.i = u << 16; return x.f;
}
__device__ __forceinline__ float bfhi(uint32_t u) {
    union { uint32_t i; float f; } x; x.i = u & 0xFFFF0000u; return x.f;
}
__device__ __forceinline__ void pk_atomic_add_bf16(void* addr, uint32_t data) {
    asm volatile("global_atomic_pk_add_bf16 %0, %1, off"
                 :: "v"((uint64_t)(uintptr_t)addr), "v"(data) : "memory");
}

// ---------------------------------------------------------------------------
// k1 (MFMA): h1pre = x @ Wlin + blin. One wave per 16-node chunk, grid-stride.
// ---------------------------------------------------------------------------
__global__ __launch_bounds__(256) void k1_lin(
    const float* __restrict__ x, const float* __restrict__ Wlin,
    const float* __restrict__ blin, float* __restrict__ h1pre, int n)
{
    const int lane = threadIdx.x & 63;
    const int g = lane >> 4, m = lane & 15;

    f16x8 Bf[6][2];
    #pragma unroll
    for (int s = 0; s < 6; ++s) {
        #pragma unroll
        for (int i = 0; i < 8; ++i) {
            const int k = s * 32 + g * 8 + i;
            Bf[s][0][i] = (_Float16)((k < FIN) ? Wlin[k * 32 + m] : 0.f);
            Bf[s][1][i] = (_Float16)((k < FIN) ? Wlin[k * 32 + 16 + m] : 0.f);
        }
    }
    const float b0 = blin[m], b1 = blin[16 + m];

    const int wid = blockIdx.x * 4 + (threadIdx.x >> 6);
    const int nW  = gridDim.x * 4;
    const int nChunks = (n + 15) / 16;

    for (int c = wid; c < nChunks; c += nW) {
        const int row = c * 16 + m;
        const bool rv = row < n;
        const float* xr = x + (size_t)row * FIN;

        f32x4 acc0 = {0.f, 0.f, 0.f, 0.f};
        f32x4 acc1 = {0.f, 0.f, 0.f, 0.f};
        #pragma unroll
        for (int s = 0; s < 6; ++s) {
            f16x8 A;
            #pragma unroll
            for (int i = 0; i < 8; ++i) {
                const int k = s * 32 + g * 8 + i;
                A[i] = (_Float16)((rv && k < FIN) ? xr[k] : 0.f);
            }
            acc0 = __builtin_amdgcn_mfma_f32_16x16x32_f16(A, Bf[s][0], acc0, 0, 0, 0);
            acc1 = __builtin_amdgcn_mfma_f32_16x16x32_f16(A, Bf[s][1], acc1, 0, 0, 0);
        }
        #pragma unroll
        for (int r = 0; r < 4; ++r) {
            const int node = c * 16 + 4 * g + r;
            if (node < n) {
                h1pre[(size_t)node * 32 + m]      = acc0[r] + b0;
                h1pre[(size_t)node * 32 + 16 + m] = acc1[r] + b1;
            }
        }
    }
}

// ---------------------------------------------------------------------------
template <int K, int O>
__device__ __forceinline__ void matvecKO(const float* __restrict__ v,
                                         const float* __restrict__ W,
                                         const float* __restrict__ B,
                                         float* __restrict__ out)
{
    #pragma unroll
    for (int o4 = 0; o4 < O / 4; ++o4) {
        float a0 = B[o4 * 4 + 0], a1 = B[o4 * 4 + 1];
        float a2 = B[o4 * 4 + 2], a3 = B[o4 * 4 + 3];
        #pragma unroll
        for (int k = 0; k < K; ++k) {
            float4 wv = *reinterpret_cast<const float4*>(&W[k * O + o4 * 4]);
            float hv = v[k];
            a0 = fmaf(hv, wv.x, a0);
            a1 = fmaf(hv, wv.y, a1);
            a2 = fmaf(hv, wv.z, a2);
            a3 = fmaf(hv, wv.w, a3);
        }
        out[o4 * 4 + 0] = a0; out[o4 * 4 + 1] = a1;
        out[o4 * 4 + 2] = a2; out[o4 * 4 + 3] = a3;
    }
}

// ---------------------------------------------------------------------------
// k2: thread phase — encoders + gating -> v40 (LDS, f16);
//     wave phase  — comb + Q/K/V/skip MFMAs; skip projected onto Wout
//     (16-lane reduce) -> skip2[node] = (skip@Wout[:,0], skip@Wout[:,1]).
// ---------------------------------------------------------------------------
__global__ __launch_bounds__(256) void k2_enc(
    const float* __restrict__ h1pre,
    const float* __restrict__ node_interval, const float* __restrict__ node_degree,
    const float* __restrict__ Wtf, const float* __restrict__ btf,
    const float* __restrict__ Wd,  const float* __restrict__ bd,
    const float* __restrict__ Wenc, const float* __restrict__ benc,
    const float* __restrict__ Wx,  const float* __restrict__ bx,
    const float* __restrict__ Wcomb, const float* __restrict__ bcomb,
    const float* __restrict__ Wq,  const float* __restrict__ bq,
    const float* __restrict__ Wk,  const float* __restrict__ bk,
    const float* __restrict__ Wv,  const float* __restrict__ bv,
    const float* __restrict__ Wskip, const float* __restrict__ bskip,
    const float* __restrict__ Wout,
    uint32_t* __restrict__ q32, uint32_t* __restrict__ kv32,
    float2* __restrict__ skip2, int n)
{
    __shared__ __align__(16) float sWenc[64], sWx[256];
    __shared__ float sWtf[8], sbtf[8], sWd[8], sbd[8], sbenc[8], sbx[8];
    __shared__ __align__(16) _Float16 v40s[256][72];
    __shared__ __align__(16) _Float16 h1s[256][40];

    const int t = threadIdx.x;
    if (t < 8) {
        sWtf[t] = Wtf[t]; sbtf[t] = btf[t];
        sWd[t]  = Wd[t];  sbd[t]  = bd[t];
        sbenc[t] = benc[t]; sbx[t] = bx[t];
    }
    if (t < 64) sWenc[t] = Wenc[t];
    if (t < 256) sWx[t] = Wx[t];

    const int nid = blockIdx.x * 256 + t;
    const bool active = nid < n;

    __syncthreads();

    if (active) {
        float h1p[32];
        const float2* hp = reinterpret_cast<const float2*>(h1pre + (size_t)nid * 32);
        #pragma unroll
        for (int i = 0; i < 16; ++i) {
            float2 v2 = hp[i];
            h1p[2 * i] = v2.x; h1p[2 * i + 1] = v2.y;
        }
        const float ti = node_interval[nid], dg = node_degree[nid];
        float tf[8], de[8];
        #pragma unroll
        for (int j = 0; j < 8; ++j) {
            tf[j] = fmaf(ti, sWtf[j], sbtf[j]);
            de[j] = fmaf(dg, sWd[j], sbd[j]);
        }
        float xp[8];
        matvecKO<32, 8>(h1p, sWx, sbx, xp);
        #pragma unroll
        for (int o = 0; o < 8; ++o) xp[o] = tanhf(xp[o]);

        float ep0[8], ep1[8];
        matvecKO<8, 8>(tf, sWenc, sbenc, ep0);
        matvecKO<8, 8>(de, sWenc, sbenc, ep1);
        float sc0 = 0.f, sc1 = 0.f;
        #pragma unroll
        for (int o = 0; o < 8; ++o) {
            sc0 = fmaf(tanhf(ep0[o]), xp[o], sc0);
            sc1 = fmaf(tanhf(ep1[o]), xp[o], sc1);
        }
        const float mm = fmaxf(sc0, sc1);
        const float e0 = __expf(sc0 - mm), e1 = __expf(sc1 - mm);
        const float inv = 1.f / (e0 + e1);
        const float s0 = e0 * inv, s1 = e1 * inv;

        #pragma unroll
        for (int i = 0; i < 32; ++i) v40s[t][i] = (_Float16)h1p[i];
        #pragma unroll
        for (int j = 0; j < 8; ++j)
            v40s[t][32 + j] = (_Float16)fmaf(s0, tf[j], s1 * de[j]);
    } else {
        #pragma unroll
        for (int i = 0; i < 40; ++i) v40s[t][i] = (_Float16)0.f;
    }
    #pragma unroll
    for (int i = 40; i < 64; ++i) v40s[t][i] = (_Float16)0.f;

    __syncthreads();

    const int lane = t & 63;
    const int g = lane >> 4, m = lane & 15;
    const int wv = t >> 6;
    const int node0 = blockIdx.x * 256;

    f16x8 Bc0[2], Bc1[2];
    #pragma unroll
    for (int s = 0; s < 2; ++s)
        #pragma unroll
        for (int i = 0; i < 8; ++i) {
            const int k = s * 32 + g * 8 + i;
            Bc0[s][i] = (_Float16)((k < 40) ? Wcomb[k * 32 + m] : 0.f);
            Bc1[s][i] = (_Float16)((k < 40) ? Wcomb[k * 32 + 16 + m] : 0.f);
        }
    const float bc0 = bcomb[m], bc1 = bcomb[16 + m];

    for (int c = wv; c < 16; c += 4) {
        f32x4 a0 = {0.f, 0.f, 0.f, 0.f};
        f32x4 a1 = {0.f, 0.f, 0.f, 0.f};
        #pragma unroll
        for (int s = 0; s < 2; ++s) {
            const f16x8 A = *reinterpret_cast<const f16x8*>(&v40s[c * 16 + m][s * 32 + g * 8]);
            a0 = __builtin_amdgcn_mfma_f32_16x16x32_f16(A, Bc0[s], a0, 0, 0, 0);
            a1 = __builtin_amdgcn_mfma_f32_16x16x32_f16(A, Bc1[s], a1, 0, 0, 0);
        }
        #pragma unroll
        for (int r = 0; r < 4; ++r) {
            const int nb = c * 16 + 4 * g + r;
            h1s[nb][m]      = (_Float16)(a0[r] + bc0);
            h1s[nb][16 + m] = (_Float16)(a1[r] + bc1);
        }
    }
    __syncthreads();

    f16x8 Bq0, Bq1, Bk0, Bk1, Bv0, Bv1, Bs0, Bs1;
    #pragma unroll
    for (int i = 0; i < 8; ++i) {
        const int k = g * 8 + i;
        Bq0[i] = (_Float16)Wq[k * 32 + m];     Bq1[i] = (_Float16)Wq[k * 32 + 16 + m];
        Bk0[i] = (_Float16)Wk[k * 32 + m];     Bk1[i] = (_Float16)Wk[k * 32 + 16 + m];
        Bv0[i] = (_Float16)Wv[k * 32 + m];     Bv1[i] = (_Float16)Wv[k * 32 + 16 + m];
        Bs0[i] = (_Float16)Wskip[k * 32 + m];  Bs1[i] = (_Float16)Wskip[k * 32 + 16 + m];
    }
    const float bq0 = bq[m], bq1 = bq[16 + m];
    const float bk0 = bk[m], bk1 = bk[16 + m];
    const float bv0 = bv[m], bv1 = bv[16 + m];
    const float bs0 = bskip[m], bs1 = bskip[16 + m];
    const float wo00 = Wout[m * 2],        wo01 = Wout[m * 2 + 1];
    const float wo10 = Wout[(16 + m) * 2], wo11 = Wout[(16 + m) * 2 + 1];

    for (int c = wv; c < 16; c += 4) {
        const f16x8 A = *reinterpret_cast<const f16x8*>(&h1s[c * 16 + m][g * 8]);

        f32x4 aq0 = {0.f,0.f,0.f,0.f}, aq1 = {0.f,0.f,0.f,0.f};
        f32x4 ak0 = {0.f,0.f,0.f,0.f}, ak1 = {0.f,0.f,0.f,0.f};
        f32x4 av0 = {0.f,0.f,0.f,0.f}, av1 = {0.f,0.f,0.f,0.f};
        f32x4 as0 = {0.f,0.f,0.f,0.f}, as1 = {0.f,0.f,0.f,0.f};
        aq0 = __builtin_amdgcn_mfma_f32_16x16x32_f16(A, Bq0, aq0, 0, 0, 0);
        aq1 = __builtin_amdgcn_mfma_f32_16x16x32_f16(A, Bq1, aq1, 0, 0, 0);
        ak0 = __builtin_amdgcn_mfma_f32_16x16x32_f16(A, Bk0, ak0, 0, 0, 0);
        ak1 = __builtin_amdgcn_mfma_f32_16x16x32_f16(A, Bk1, ak1, 0, 0, 0);
        av0 = __builtin_amdgcn_mfma_f32_16x16x32_f16(A, Bv0, av0, 0, 0, 0);
        av1 = __builtin_amdgcn_mfma_f32_16x16x32_f16(A, Bv1, av1, 0, 0, 0);
        as0 = __builtin_amdgcn_mfma_f32_16x16x32_f16(A, Bs0, as0, 0, 0, 0);
        as1 = __builtin_amdgcn_mfma_f32_16x16x32_f16(A, Bs1, as1, 0, 0, 0);

        #pragma unroll
        for (int r = 0; r < 4; ++r) {
            const int node = node0 + c * 16 + 4 * g + r;
            const float sv0 = as0[r] + bs0, sv1 = as1[r] + bs1;
            // skip @ Wout: reduce over the 16 channels of the group
            float u0 = fmaf(sv0, wo00, sv1 * wo10);
            float u1 = fmaf(sv0, wo01, sv1 * wo11);
            #pragma unroll
            for (int s = 1; s < 16; s <<= 1) {
                u0 += __shfl_xor(u0, s);
                u1 += __shfl_xor(u1, s);
            }
            if (node < n) {
                q32[(size_t)node * 16 + m] =
                    cvt_pk_bf16(aq0[r] + bq0, aq1[r] + bq1);
                uint2 kvd;
                kvd.x = cvt_pk_bf16(ak0[r] + bk0, ak1[r] + bk1);
                kvd.y = cvt_pk_bf16(av0[r] + bv0, av1[r] + bv1);
                *reinterpret_cast<uint2*>(kv32 + (size_t)node * 32 + 2 * m) = kvd;
                if (m == 0) skip2[node] = make_float2(u0, u1);
            }
        }
    }
}

// ---------------------------------------------------------------------------
// k3: edge kernel — r8 skeleton (16 lanes/edge, coalesced vector gathers,
// stage-1 prefetch, MFMA edge features, 16-lane p-reduce) with the
// project-before-scatter tail: per edge, message projected onto Wout in-lane,
// 4-chain 16-lane reduce, then 3 pk-bf16 atomics from lanes m=0,1,2 into one
// private 64B row acc[dst][32] = {Y00,Y01, Y10,Y11, den0,den1, ...pad}.
// ---------------------------------------------------------------------------
__global__ __launch_bounds__(256) void k3_edge(
    const int* __restrict__ ei, const float* __restrict__ node_time,
    const float* __restrict__ edge_time,
    const uint32_t* __restrict__ qp, const uint32_t* __restrict__ kvp,
    const float* __restrict__ Wt, const float* __restrict__ bt,
    const float* __restrict__ We, const float* __restrict__ be,
    const float* __restrict__ Wout,
    unsigned short* __restrict__ acc, int numE, int nTiles)
{
    const int lane = threadIdx.x & 63;
    const int g = lane >> 4;
    const int m = lane & 15;

    float wtr[8], btr[8];
    f16x8 B0, B1;
    #pragma unroll
    for (int i = 0; i < 8; ++i) {
        const int k = g * 8 + i;
        wtr[i] = Wt[k];
        btr[i] = bt[k];
        B0[i] = (_Float16)We[k * 32 + m];
        B1[i] = (_Float16)We[k * 32 + 16 + m];
    }
    const float be0 = be[m], be1 = be[16 + m];
    const float wo00 = Wout[m * 2],        wo01 = Wout[m * 2 + 1];
    const float wo10 = Wout[(16 + m) * 2], wo11 = Wout[(16 + m) * 2 + 1];

    const int wid = blockIdx.x * (blockDim.x >> 6) + (threadIdx.x >> 6);
    const int nW  = gridDim.x * (blockDim.x >> 6);

    int tile = wid;
    if (tile >= nTiles) return;

    int srcm = 0, dstm = 0;
    float et = 0.f;
    {
        const int eA = tile * 16 + m;
        if (eA < numE) {
            srcm = ei[eA];
            dstm = ei[numE + eA];
            et   = edge_time[eA];
        }
    }

    while (true) {
        const float nt = node_time[srcm];
        int srcr[4], dstr[4];
        uint32_t qw[4];
        uint2 kvw[4];
        #pragma unroll
        for (int r = 0; r < 4; ++r) {
            const int j = g * 4 + r;
            srcr[r] = __shfl(srcm, j);
            dstr[r] = __shfl(dstm, j);
            qw[r]  = qp[(size_t)dstr[r] * 16 + m];
            kvw[r] = *reinterpret_cast<const uint2*>(
                         kvp + (size_t)srcr[r] * 32 + 2 * m);
        }

        const int ntile = tile + nW;
        int nsrc = 0, ndst = 0;
        float net = 0.f;
        if (ntile < nTiles) {
            const int eA = ntile * 16 + m;
            if (eA < numE) {
                nsrc = ei[eA];
                ndst = ei[numE + eA];
                net  = edge_time[eA];
            }
        }

        const float rel = nt - et;
        f16x8 A;
        #pragma unroll
        for (int i = 0; i < 8; ++i)
            A[i] = (_Float16)__cosf(fmaf(rel, wtr[i], btr[i]));

        f32x4 acc0 = {0.f, 0.f, 0.f, 0.f};
        f32x4 acc1 = {0.f, 0.f, 0.f, 0.f};
        acc0 = __builtin_amdgcn_mfma_f32_16x16x32_f16(A, B0, acc0, 0, 0, 0);
        acc1 = __builtin_amdgcn_mfma_f32_16x16x32_f16(A, B1, acc1, 0, 0, 0);

        const int e0 = tile * 16;
        #pragma unroll
        for (int r = 0; r < 4; ++r) {
            if (e0 + g * 4 + r < numE) {
                const float ef0 = acc0[r] + be0;
                const float ef1 = acc1[r] + be1;

                const uint32_t uq = qw[r];
                const uint32_t uk = kvw[r].x, uv = kvw[r].y;
                const float q0 = bflo(uq), q1 = bfhi(uq);
                const float k0 = bflo(uk), k1 = bfhi(uk);
                const float v0 = bflo(uv), v1 = bfhi(uv);

                float p0 = q0 * (k0 + ef0);
                float p1 = q1 * (k1 + ef1);
                #pragma unroll
                for (int s = 1; s < 16; s <<= 1) {
                    p0 += __shfl_xor(p0, s);
                    p1 += __shfl_xor(p1, s);
                }
                const float w0 = __expf(p0 * INV_SQRT_C);
                const float w1 = __expf(p1 * INV_SQRT_C);

                // project message onto Wout (per-head), reduce over channels
                const float t0 = w0 * (v0 + ef0);      // head-0 channel m
                const float t1 = w1 * (v1 + ef1);      // head-1 channel m
                float u00 = t0 * wo00, u01 = t0 * wo01;
                float u10 = t1 * wo10, u11 = t1 * wo11;
                #pragma unroll
                for (int s = 1; s < 16; s <<= 1) {
                    u00 += __shfl_xor(u00, s); u01 += __shfl_xor(u01, s);
                    u10 += __shfl_xor(u10, s); u11 += __shfl_xor(u11, s);
                }

                unsigned short* row = acc + (size_t)dstr[r] * 32;
                if (m == 0) pk_atomic_add_bf16(row,     cvt_pk_bf16(u00, u01));
                if (m == 1) pk_atomic_add_bf16(row + 2, cvt_pk_bf16(u10, u11));
                if (m == 2) pk_atomic_add_bf16(row + 4, cvt_pk_bf16(w0,  w1));
            }
        }

        if (ntile >= nTiles) break;
        tile = ntile; srcm = nsrc; dstm = ndst; et = net;
    }
}

// ---------------------------------------------------------------------------
// k4: out = log_softmax(Y0./den0 + Y1./den1 + skip2 + bout).  24B in, 8B out.
// ---------------------------------------------------------------------------
__global__ __launch_bounds__(256) void k4_out(
    const unsigned short* __restrict__ acc, const float2* __restrict__ skip2,
    const float* __restrict__ bout, float* __restrict__ out, int n)
{
    const int nid = blockIdx.x * 256 + threadIdx.x;
    if (nid >= n) return;

    const uint4 u = *reinterpret_cast<const uint4*>(acc + (size_t)nid * 32);
    const float inv0 = 1.f / (bflo(u.z) + 1e-16f);   // den0
    const float inv1 = 1.f / (bfhi(u.z) + 1e-16f);   // den1
    const float2 sk = skip2[nid];

    const float o0 = bflo(u.x) * inv0 + bflo(u.y) * inv1 + sk.x + bout[0];
    const float o1 = bfhi(u.x) * inv0 + bfhi(u.y) * inv1 + sk.y + bout[1];

    const float mm = fmaxf(o0, o1);
    const float lse = mm + __logf(__expf(o0 - mm) + __expf(o1 - mm));
    out[(size_t)nid * 2 + 0] = o0 - lse;
    out[(size_t)nid * 2 + 1] = o1 - lse;
}

// ---------------------------------------------------------------------------
extern "C" void kernel_launch(void* const* d_in, const int* in_sizes, int n_in,
                              void* d_out, int out_size, void* d_ws, size_t ws_size,
                              hipStream_t stream)
{
    const float* x             = (const float*)d_in[0];
    const int*   ei            = (const int*)  d_in[1];
    const float* node_time     = (const float*)d_in[2];
    const float* edge_time     = (const float*)d_in[3];
    const float* node_interval = (const float*)d_in[4];
    const float* node_degree   = (const float*)d_in[5];
    const float* Wt    = (const float*)d_in[6];  const float* bt    = (const float*)d_in[7];
    const float* Wd    = (const float*)d_in[8];  const float* bd    = (const float*)d_in[9];
    const float* Wtf   = (const float*)d_in[10]; const float* btf   = (const float*)d_in[11];
    const float* Wenc  = (const float*)d_in[12]; const float* benc  = (const float*)d_in[13];
    const float* Wx    = (const float*)d_in[14]; const float* bx    = (const float*)d_in[15];
    const float* Wlin  = (const float*)d_in[16]; const float* blin  = (const float*)d_in[17];
    const float* Wcomb = (const float*)d_in[18]; const float* bcomb = (const float*)d_in[19];
    const float* Wq    = (const float*)d_in[20]; const float* bq    = (const float*)d_in[21];
    const float* Wk    = (const float*)d_in[22]; const float* bk    = (const float*)d_in[23];
    const float* Wv    = (const float*)d_in[24]; const float* bv    = (const float*)d_in[25];
    const float* We    = (const float*)d_in[26]; const float* be    = (const float*)d_in[27];
    const float* Wskip = (const float*)d_in[28]; const float* bskip = (const float*)d_in[29];
    const float* Wout  = (const float*)d_in[30]; const float* bout  = (const float*)d_in[31];

    const int n    = in_sizes[2];   // node_time: [N]
    const int numE = in_sizes[3];   // edge_time: [E,1]

    // ---- workspace carve (bytes) ----
    char* base = (char*)d_ws;
    uint32_t* q32  = (uint32_t*)base; base += (size_t)n * 16 * 4;   // q pairs
    uint32_t* kv32 = (uint32_t*)base; base += (size_t)n * 32 * 4;   // kv quads
    float* h1pre = (float*)base; base += (size_t)n * 32 * 4;
    float2* skip2 = (float2*)base; base += (size_t)n * 2 * 4;
    unsigned short* acc = (unsigned short*)base; base += (size_t)n * 32 * 2;

    // zero the atomic accumulator rows
    hipMemsetAsync(acc, 0, (size_t)n * 32 * 2, stream);

    k1_lin<<<512, 256, 0, stream>>>(x, Wlin, blin, h1pre, n);

    k2_enc<<<(n + 255) / 256, 256, 0, stream>>>(
        h1pre, node_interval, node_degree,
        Wtf, btf, Wd, bd, Wenc, benc, Wx, bx, Wcomb, bcomb,
        Wq, bq, Wk, bk, Wv, bv, Wskip, bskip, Wout,
        q32, kv32, skip2, n);

    const int nTiles = (numE + 15) / 16;
    k3_edge<<<4096, 256, 0, stream>>>(
        ei, node_time, edge_time, q32, kv32,
        Wt, bt, We, be, Wout, acc, numE, nTiles);

    k4_out<<<(n + 255) / 256, 256, 0, stream>>>(
        acc, skip2, bout, (float*)d_out, n);
}

// Round 12
// 576.168 us; speedup vs baseline: 1.0076x; 1.0076x over previous
//
#include <hip/hip_runtime.h>
#include <hip/hip_bf16.h>
#include <cstdint>

// TGAT fused pipeline for MI355X — round 11: r8 k3 skeleton + project-before-
// scatter backend (6 scalars/edge, per-head denominators, private 64B rows).
//   k1: h1pre = x @ Wlin + blin  via mfma_16x16x32_f16
//   k2: encoders per-thread; comb + Q/K/V/skip as block MFMAs; skip projected
//       onto Wout in-kernel -> skip2 (f32x2/node)
//   k3: edge kernel — r8 gather/MFMA/p-reduce; tail projects message onto
//       Wout, 16-lane reduce, 3 pk-bf16 atomics into acc[dst][32] (one line)
//   k4: out = log_softmax(Y0./den0 + Y1./den1 + skip2 + bout)

#define FIN 172
#define INV_SQRT_C 0.25f

typedef _Float16 f16x8 __attribute__((ext_vector_type(8)));
typedef float f32x4 __attribute__((ext_vector_type(4)));

__device__ __forceinline__ uint32_t cvt_pk_bf16(float lo, float hi) {
    uint32_t r;
    asm("v_cvt_pk_bf16_f32 %0, %1, %2" : "=v"(r) : "v"(lo), "v"(hi));
    return r;
}
__device__ __forceinline__ float bflo(uint32_t u) {
    union { uint32_t i; float f; } x; x.i = u << 16; return x.f;
}
__device__ __forceinline__ float bfhi(uint32_t u) {
    union { uint32_t i; float f; } x; x.i = u & 0xFFFF0000u; return x.f;
}
__device__ __forceinline__ void pk_atomic_add_bf16(void* addr, uint32_t data) {
    asm volatile("global_atomic_pk_add_bf16 %0, %1, off"
                 :: "v"((uint64_t)(uintptr_t)addr), "v"(data) : "memory");
}

// ---------------------------------------------------------------------------
// k1 (MFMA): h1pre = x @ Wlin + blin. One wave per 16-node chunk, grid-stride.
// ---------------------------------------------------------------------------
__global__ __launch_bounds__(256) void k1_lin(
    const float* __restrict__ x, const float* __restrict__ Wlin,
    const float* __restrict__ blin, float* __restrict__ h1pre, int n)
{
    const int lane = threadIdx.x & 63;
    const int g = lane >> 4, m = lane & 15;

    f16x8 Bf[6][2];
    #pragma unroll
    for (int s = 0; s < 6; ++s) {
        #pragma unroll
        for (int i = 0; i < 8; ++i) {
            const int k = s * 32 + g * 8 + i;
            Bf[s][0][i] = (_Float16)((k < FIN) ? Wlin[k * 32 + m] : 0.f);
            Bf[s][1][i] = (_Float16)((k < FIN) ? Wlin[k * 32 + 16 + m] : 0.f);
        }
    }
    const float b0 = blin[m], b1 = blin[16 + m];

    const int wid = blockIdx.x * 4 + (threadIdx.x >> 6);
    const int nW  = gridDim.x * 4;
    const int nChunks = (n + 15) / 16;

    for (int c = wid; c < nChunks; c += nW) {
        const int row = c * 16 + m;
        const bool rv = row < n;
        const float* xr = x + (size_t)row * FIN;

        f32x4 acc0 = {0.f, 0.f, 0.f, 0.f};
        f32x4 acc1 = {0.f, 0.f, 0.f, 0.f};
        #pragma unroll
        for (int s = 0; s < 6; ++s) {
            f16x8 A;
            #pragma unroll
            for (int i = 0; i < 8; ++i) {
                const int k = s * 32 + g * 8 + i;
                A[i] = (_Float16)((rv && k < FIN) ? xr[k] : 0.f);
            }
            acc0 = __builtin_amdgcn_mfma_f32_16x16x32_f16(A, Bf[s][0], acc0, 0, 0, 0);
            acc1 = __builtin_amdgcn_mfma_f32_16x16x32_f16(A, Bf[s][1], acc1, 0, 0, 0);
        }
        #pragma unroll
        for (int r = 0; r < 4; ++r) {
            const int node = c * 16 + 4 * g + r;
            if (node < n) {
                h1pre[(size_t)node * 32 + m]      = acc0[r] + b0;
                h1pre[(size_t)node * 32 + 16 + m] = acc1[r] + b1;
            }
        }
    }
}

// ---------------------------------------------------------------------------
template <int K, int O>
__device__ __forceinline__ void matvecKO(const float* __restrict__ v,
                                         const float* __restrict__ W,
                                         const float* __restrict__ B,
                                         float* __restrict__ out)
{
    #pragma unroll
    for (int o4 = 0; o4 < O / 4; ++o4) {
        float a0 = B[o4 * 4 + 0], a1 = B[o4 * 4 + 1];
        float a2 = B[o4 * 4 + 2], a3 = B[o4 * 4 + 3];
        #pragma unroll
        for (int k = 0; k < K; ++k) {
            float4 wv = *reinterpret_cast<const float4*>(&W[k * O + o4 * 4]);
            float hv = v[k];
            a0 = fmaf(hv, wv.x, a0);
            a1 = fmaf(hv, wv.y, a1);
            a2 = fmaf(hv, wv.z, a2);
            a3 = fmaf(hv, wv.w, a3);
        }
        out[o4 * 4 + 0] = a0; out[o4 * 4 + 1] = a1;
        out[o4 * 4 + 2] = a2; out[o4 * 4 + 3] = a3;
    }
}

// ---------------------------------------------------------------------------
// k2: thread phase — encoders + gating -> v40 (LDS, f16);
//     wave phase  — comb + Q/K/V/skip MFMAs; skip projected onto Wout
//     (16-lane reduce) -> skip2[node] = (skip@Wout[:,0], skip@Wout[:,1]).
// ---------------------------------------------------------------------------
__global__ __launch_bounds__(256) void k2_enc(
    const float* __restrict__ h1pre,
    const float* __restrict__ node_interval, const float* __restrict__ node_degree,
    const float* __restrict__ Wtf, const float* __restrict__ btf,
    const float* __restrict__ Wd,  const float* __restrict__ bd,
    const float* __restrict__ Wenc, const float* __restrict__ benc,
    const float* __restrict__ Wx,  const float* __restrict__ bx,
    const float* __restrict__ Wcomb, const float* __restrict__ bcomb,
    const float* __restrict__ Wq,  const float* __restrict__ bq,
    const float* __restrict__ Wk,  const float* __restrict__ bk,
    const float* __restrict__ Wv,  const float* __restrict__ bv,
    const float* __restrict__ Wskip, const float* __restrict__ bskip,
    const float* __restrict__ Wout,
    uint32_t* __restrict__ q32, uint32_t* __restrict__ kv32,
    float2* __restrict__ skip2, int n)
{
    __shared__ __align__(16) float sWenc[64], sWx[256];
    __shared__ float sWtf[8], sbtf[8], sWd[8], sbd[8], sbenc[8], sbx[8];
    __shared__ __align__(16) _Float16 v40s[256][72];
    __shared__ __align__(16) _Float16 h1s[256][40];

    const int t = threadIdx.x;
    if (t < 8) {
        sWtf[t] = Wtf[t]; sbtf[t] = btf[t];
        sWd[t]  = Wd[t];  sbd[t]  = bd[t];
        sbenc[t] = benc[t]; sbx[t] = bx[t];
    }
    if (t < 64) sWenc[t] = Wenc[t];
    if (t < 256) sWx[t] = Wx[t];

    const int nid = blockIdx.x * 256 + t;
    const bool active = nid < n;

    __syncthreads();

    if (active) {
        float h1p[32];
        const float2* hp = reinterpret_cast<const float2*>(h1pre + (size_t)nid * 32);
        #pragma unroll
        for (int i = 0; i < 16; ++i) {
            float2 v2 = hp[i];
            h1p[2 * i] = v2.x; h1p[2 * i + 1] = v2.y;
        }
        const float ti = node_interval[nid], dg = node_degree[nid];
        float tf[8], de[8];
        #pragma unroll
        for (int j = 0; j < 8; ++j) {
            tf[j] = fmaf(ti, sWtf[j], sbtf[j]);
            de[j] = fmaf(dg, sWd[j], sbd[j]);
        }
        float xp[8];
        matvecKO<32, 8>(h1p, sWx, sbx, xp);
        #pragma unroll
        for (int o = 0; o < 8; ++o) xp[o] = tanhf(xp[o]);

        float ep0[8], ep1[8];
        matvecKO<8, 8>(tf, sWenc, sbenc, ep0);
        matvecKO<8, 8>(de, sWenc, sbenc, ep1);
        float sc0 = 0.f, sc1 = 0.f;
        #pragma unroll
        for (int o = 0; o < 8; ++o) {
            sc0 = fmaf(tanhf(ep0[o]), xp[o], sc0);
            sc1 = fmaf(tanhf(ep1[o]), xp[o], sc1);
        }
        const float mm = fmaxf(sc0, sc1);
        const float e0 = __expf(sc0 - mm), e1 = __expf(sc1 - mm);
        const float inv = 1.f / (e0 + e1);
        const float s0 = e0 * inv, s1 = e1 * inv;

        #pragma unroll
        for (int i = 0; i < 32; ++i) v40s[t][i] = (_Float16)h1p[i];
        #pragma unroll
        for (int j = 0; j < 8; ++j)
            v40s[t][32 + j] = (_Float16)fmaf(s0, tf[j], s1 * de[j]);
    } else {
        #pragma unroll
        for (int i = 0; i < 40; ++i) v40s[t][i] = (_Float16)0.f;
    }
    #pragma unroll
    for (int i = 40; i < 64; ++i) v40s[t][i] = (_Float16)0.f;

    __syncthreads();

    const int lane = t & 63;
    const int g = lane >> 4, m = lane & 15;
    const int wv = t >> 6;
    const int node0 = blockIdx.x * 256;

    f16x8 Bc0[2], Bc1[2];
    #pragma unroll
    for (int s = 0; s < 2; ++s)
        #pragma unroll
        for (int i = 0; i < 8; ++i) {
            const int k = s * 32 + g * 8 + i;
            Bc0[s][i] = (_Float16)((k < 40) ? Wcomb[k * 32 + m] : 0.f);
            Bc1[s][i] = (_Float16)((k < 40) ? Wcomb[k * 32 + 16 + m] : 0.f);
        }
    const float bc0 = bcomb[m], bc1 = bcomb[16 + m];

    for (int c = wv; c < 16; c += 4) {
        f32x4 a0 = {0.f, 0.f, 0.f, 0.f};
        f32x4 a1 = {0.f, 0.f, 0.f, 0.f};
        #pragma unroll
        for (int s = 0; s < 2; ++s) {
            const f16x8 A = *reinterpret_cast<const f16x8*>(&v40s[c * 16 + m][s * 32 + g * 8]);
            a0 = __builtin_amdgcn_mfma_f32_16x16x32_f16(A, Bc0[s], a0, 0, 0, 0);
            a1 = __builtin_amdgcn_mfma_f32_16x16x32_f16(A, Bc1[s], a1, 0, 0, 0);
        }
        #pragma unroll
        for (int r = 0; r < 4; ++r) {
            const int nb = c * 16 + 4 * g + r;
            h1s[nb][m]      = (_Float16)(a0[r] + bc0);
            h1s[nb][16 + m] = (_Float16)(a1[r] + bc1);
        }
    }
    __syncthreads();

    f16x8 Bq0, Bq1, Bk0, Bk1, Bv0, Bv1, Bs0, Bs1;
    #pragma unroll
    for (int i = 0; i < 8; ++i) {
        const int k = g * 8 + i;
        Bq0[i] = (_Float16)Wq[k * 32 + m];     Bq1[i] = (_Float16)Wq[k * 32 + 16 + m];
        Bk0[i] = (_Float16)Wk[k * 32 + m];     Bk1[i] = (_Float16)Wk[k * 32 + 16 + m];
        Bv0[i] = (_Float16)Wv[k * 32 + m];     Bv1[i] = (_Float16)Wv[k * 32 + 16 + m];
        Bs0[i] = (_Float16)Wskip[k * 32 + m];  Bs1[i] = (_Float16)Wskip[k * 32 + 16 + m];
    }
    const float bq0 = bq[m], bq1 = bq[16 + m];
    const float bk0 = bk[m], bk1 = bk[16 + m];
    const float bv0 = bv[m], bv1 = bv[16 + m];
    const float bs0 = bskip[m], bs1 = bskip[16 + m];
    const float wo00 = Wout[m * 2],        wo01 = Wout[m * 2 + 1];
    const float wo10 = Wout[(16 + m) * 2], wo11 = Wout[(16 + m) * 2 + 1];

    for (int c = wv; c < 16; c += 4) {
        const f16x8 A = *reinterpret_cast<const f16x8*>(&h1s[c * 16 + m][g * 8]);

        f32x4 aq0 = {0.f,0.f,0.f,0.f}, aq1 = {0.f,0.f,0.f,0.f};
        f32x4 ak0 = {0.f,0.f,0.f,0.f}, ak1 = {0.f,0.f,0.f,0.f};
        f32x4 av0 = {0.f,0.f,0.f,0.f}, av1 = {0.f,0.f,0.f,0.f};
        f32x4 as0 = {0.f,0.f,0.f,0.f}, as1 = {0.f,0.f,0.f,0.f};
        aq0 = __builtin_amdgcn_mfma_f32_16x16x32_f16(A, Bq0, aq0, 0, 0, 0);
        aq1 = __builtin_amdgcn_mfma_f32_16x16x32_f16(A, Bq1, aq1, 0, 0, 0);
        ak0 = __builtin_amdgcn_mfma_f32_16x16x32_f16(A, Bk0, ak0, 0, 0, 0);
        ak1 = __builtin_amdgcn_mfma_f32_16x16x32_f16(A, Bk1, ak1, 0, 0, 0);
        av0 = __builtin_amdgcn_mfma_f32_16x16x32_f16(A, Bv0, av0, 0, 0, 0);
        av1 = __builtin_amdgcn_mfma_f32_16x16x32_f16(A, Bv1, av1, 0, 0, 0);
        as0 = __builtin_amdgcn_mfma_f32_16x16x32_f16(A, Bs0, as0, 0, 0, 0);
        as1 = __builtin_amdgcn_mfma_f32_16x16x32_f16(A, Bs1, as1, 0, 0, 0);

        #pragma unroll
        for (int r = 0; r < 4; ++r) {
            const int node = node0 + c * 16 + 4 * g + r;
            const float sv0 = as0[r] + bs0, sv1 = as1[r] + bs1;
            // skip @ Wout: reduce over the 16 channels of the group
            float u0 = fmaf(sv0, wo00, sv1 * wo10);
            float u1 = fmaf(sv0, wo01, sv1 * wo11);
            #pragma unroll
            for (int s = 1; s < 16; s <<= 1) {
                u0 += __shfl_xor(u0, s);
                u1 += __shfl_xor(u1, s);
            }
            if (node < n) {
                q32[(size_t)node * 16 + m] =
                    cvt_pk_bf16(aq0[r] + bq0, aq1[r] + bq1);
                uint2 kvd;
                kvd.x = cvt_pk_bf16(ak0[r] + bk0, ak1[r] + bk1);
                kvd.y = cvt_pk_bf16(av0[r] + bv0, av1[r] + bv1);
                *reinterpret_cast<uint2*>(kv32 + (size_t)node * 32 + 2 * m) = kvd;
                if (m == 0) skip2[node] = make_float2(u0, u1);
            }
        }
    }
}

// ---------------------------------------------------------------------------
// k3: edge kernel — r8 skeleton (16 lanes/edge, coalesced vector gathers,
// stage-1 prefetch, MFMA edge features, 16-lane p-reduce) with the
// project-before-scatter tail: per edge, message projected onto Wout in-lane,
// 4-chain 16-lane reduce, then 3 pk-bf16 atomics from lanes m=0,1,2 into one
// private 64B row acc[dst][32] = {Y00,Y01, Y10,Y11, den0,den1, ...pad}.
// ---------------------------------------------------------------------------
__global__ __launch_bounds__(256) void k3_edge(
    const int* __restrict__ ei, const float* __restrict__ node_time,
    const float* __restrict__ edge_time,
    const uint32_t* __restrict__ qp, const uint32_t* __restrict__ kvp,
    const float* __restrict__ Wt, const float* __restrict__ bt,
    const float* __restrict__ We, const float* __restrict__ be,
    const float* __restrict__ Wout,
    unsigned short* __restrict__ acc, int numE, int nTiles)
{
    const int lane = threadIdx.x & 63;
    const int g = lane >> 4;
    const int m = lane & 15;

    float wtr[8], btr[8];
    f16x8 B0, B1;
    #pragma unroll
    for (int i = 0; i < 8; ++i) {
        const int k = g * 8 + i;
        wtr[i] = Wt[k];
        btr[i] = bt[k];
        B0[i] = (_Float16)We[k * 32 + m];
        B1[i] = (_Float16)We[k * 32 + 16 + m];
    }
    const float be0 = be[m], be1 = be[16 + m];
    const float wo00 = Wout[m * 2],        wo01 = Wout[m * 2 + 1];
    const float wo10 = Wout[(16 + m) * 2], wo11 = Wout[(16 + m) * 2 + 1];

    const int wid = blockIdx.x * (blockDim.x >> 6) + (threadIdx.x >> 6);
    const int nW  = gridDim.x * (blockDim.x >> 6);

    int tile = wid;
    if (tile >= nTiles) return;

    int srcm = 0, dstm = 0;
    float et = 0.f;
    {
        const int eA = tile * 16 + m;
        if (eA < numE) {
            srcm = ei[eA];
            dstm = ei[numE + eA];
            et   = edge_time[eA];
        }
    }

    while (true) {
        const float nt = node_time[srcm];
        int srcr[4], dstr[4];
        uint32_t qw[4];
        uint2 kvw[4];
        #pragma unroll
        for (int r = 0; r < 4; ++r) {
            const int j = g * 4 + r;
            srcr[r] = __shfl(srcm, j);
            dstr[r] = __shfl(dstm, j);
            qw[r]  = qp[(size_t)dstr[r] * 16 + m];
            kvw[r] = *reinterpret_cast<const uint2*>(
                         kvp + (size_t)srcr[r] * 32 + 2 * m);
        }

        const int ntile = tile + nW;
        int nsrc = 0, ndst = 0;
        float net = 0.f;
        if (ntile < nTiles) {
            const int eA = ntile * 16 + m;
            if (eA < numE) {
                nsrc = ei[eA];
                ndst = ei[numE + eA];
                net  = edge_time[eA];
            }
        }

        const float rel = nt - et;
        f16x8 A;
        #pragma unroll
        for (int i = 0; i < 8; ++i)
            A[i] = (_Float16)__cosf(fmaf(rel, wtr[i], btr[i]));

        f32x4 acc0 = {0.f, 0.f, 0.f, 0.f};
        f32x4 acc1 = {0.f, 0.f, 0.f, 0.f};
        acc0 = __builtin_amdgcn_mfma_f32_16x16x32_f16(A, B0, acc0, 0, 0, 0);
        acc1 = __builtin_amdgcn_mfma_f32_16x16x32_f16(A, B1, acc1, 0, 0, 0);

        const int e0 = tile * 16;
        #pragma unroll
        for (int r = 0; r < 4; ++r) {
            if (e0 + g * 4 + r < numE) {
                const float ef0 = acc0[r] + be0;
                const float ef1 = acc1[r] + be1;

                const uint32_t uq = qw[r];
                const uint32_t uk = kvw[r].x, uv = kvw[r].y;
                const float q0 = bflo(uq), q1 = bfhi(uq);
                const float k0 = bflo(uk), k1 = bfhi(uk);
                const float v0 = bflo(uv), v1 = bfhi(uv);

                float p0 = q0 * (k0 + ef0);
                float p1 = q1 * (k1 + ef1);
                #pragma unroll
                for (int s = 1; s < 16; s <<= 1) {
                    p0 += __shfl_xor(p0, s);
                    p1 += __shfl_xor(p1, s);
                }
                const float w0 = __expf(p0 * INV_SQRT_C);
                const float w1 = __expf(p1 * INV_SQRT_C);

                // project message onto Wout (per-head), reduce over channels
                const float t0 = w0 * (v0 + ef0);      // head-0 channel m
                const float t1 = w1 * (v1 + ef1);      // head-1 channel m
                float u00 = t0 * wo00, u01 = t0 * wo01;
                float u10 = t1 * wo10, u11 = t1 * wo11;
                #pragma unroll
                for (int s = 1; s < 16; s <<= 1) {
                    u00 += __shfl_xor(u00, s); u01 += __shfl_xor(u01, s);
                    u10 += __shfl_xor(u10, s); u11 += __shfl_xor(u11, s);
                }

                unsigned short* row = acc + (size_t)dstr[r] * 32;
                if (m == 0) pk_atomic_add_bf16(row,     cvt_pk_bf16(u00, u01));
                if (m == 1) pk_atomic_add_bf16(row + 2, cvt_pk_bf16(u10, u11));
                if (m == 2) pk_atomic_add_bf16(row + 4, cvt_pk_bf16(w0,  w1));
            }
        }

        if (ntile >= nTiles) break;
        tile = ntile; srcm = nsrc; dstm = ndst; et = net;
    }
}

// ---------------------------------------------------------------------------
// k4: out = log_softmax(Y0./den0 + Y1./den1 + skip2 + bout).  24B in, 8B out.
// ---------------------------------------------------------------------------
__global__ __launch_bounds__(256) void k4_out(
    const unsigned short* __restrict__ acc, const float2* __restrict__ skip2,
    const float* __restrict__ bout, float* __restrict__ out, int n)
{
    const int nid = blockIdx.x * 256 + threadIdx.x;
    if (nid >= n) return;

    const uint4 u = *reinterpret_cast<const uint4*>(acc + (size_t)nid * 32);
    const float inv0 = 1.f / (bflo(u.z) + 1e-16f);   // den0
    const float inv1 = 1.f / (bfhi(u.z) + 1e-16f);   // den1
    const float2 sk = skip2[nid];

    const float o0 = bflo(u.x) * inv0 + bflo(u.y) * inv1 + sk.x + bout[0];
    const float o1 = bfhi(u.x) * inv0 + bfhi(u.y) * inv1 + sk.y + bout[1];

    const float mm = fmaxf(o0, o1);
    const float lse = mm + __logf(__expf(o0 - mm) + __expf(o1 - mm));
    out[(size_t)nid * 2 + 0] = o0 - lse;
    out[(size_t)nid * 2 + 1] = o1 - lse;
}

// ---------------------------------------------------------------------------
extern "C" void kernel_launch(void* const* d_in, const int* in_sizes, int n_in,
                              void* d_out, int out_size, void* d_ws, size_t ws_size,
                              hipStream_t stream)
{
    const float* x             = (const float*)d_in[0];
    const int*   ei            = (const int*)  d_in[1];
    const float* node_time     = (const float*)d_in[2];
    const float* edge_time     = (const float*)d_in[3];
    const float* node_interval = (const float*)d_in[4];
    const float* node_degree   = (const float*)d_in[5];
    const float* Wt    = (const float*)d_in[6];  const float* bt    = (const float*)d_in[7];
    const float* Wd    = (const float*)d_in[8];  const float* bd    = (const float*)d_in[9];
    const float* Wtf   = (const float*)d_in[10]; const float* btf   = (const float*)d_in[11];
    const float* Wenc  = (const float*)d_in[12]; const float* benc  = (const float*)d_in[13];
    const float* Wx    = (const float*)d_in[14]; const float* bx    = (const float*)d_in[15];
    const float* Wlin  = (const float*)d_in[16]; const float* blin  = (const float*)d_in[17];
    const float* Wcomb = (const float*)d_in[18]; const float* bcomb = (const float*)d_in[19];
    const float* Wq    = (const float*)d_in[20]; const float* bq    = (const float*)d_in[21];
    const float* Wk    = (const float*)d_in[22]; const float* bk    = (const float*)d_in[23];
    const float* Wv    = (const float*)d_in[24]; const float* bv    = (const float*)d_in[25];
    const float* We    = (const float*)d_in[26]; const float* be    = (const float*)d_in[27];
    const float* Wskip = (const float*)d_in[28]; const float* bskip = (const float*)d_in[29];
    const float* Wout  = (const float*)d_in[30]; const float* bout  = (const float*)d_in[31];

    const int n    = in_sizes[2];   // node_time: [N]
    const int numE = in_sizes[3];   // edge_time: [E,1]

    // ---- workspace carve (bytes) ----
    char* base = (char*)d_ws;
    uint32_t* q32  = (uint32_t*)base; base += (size_t)n * 16 * 4;   // q pairs
    uint32_t* kv32 = (uint32_t*)base; base += (size_t)n * 32 * 4;   // kv quads
    float* h1pre = (float*)base; base += (size_t)n * 32 * 4;
    float2* skip2 = (float2*)base; base += (size_t)n * 2 * 4;
    unsigned short* acc = (unsigned short*)base; base += (size_t)n * 32 * 2;

    // zero the atomic accumulator rows
    hipMemsetAsync(acc, 0, (size_t)n * 32 * 2, stream);

    k1_lin<<<512, 256, 0, stream>>>(x, Wlin, blin, h1pre, n);

    k2_enc<<<(n + 255) / 256, 256, 0, stream>>>(
        h1pre, node_interval, node_degree,
        Wtf, btf, Wd, bd, Wenc, benc, Wx, bx, Wcomb, bcomb,
        Wq, bq, Wk, bk, Wv, bv, Wskip, bskip, Wout,
        q32, kv32, skip2, n);

    const int nTiles = (numE + 15) / 16;
    k3_edge<<<4096, 256, 0, stream>>>(
        ei, node_time, edge_time, q32, kv32,
        Wt, bt, We, be, Wout, acc, numE, nTiles);

    k4_out<<<(n + 255) / 256, 256, 0, stream>>>(
        acc, skip2, bout, (float*)d_out, n);
}

// Round 13
// 407.528 us; speedup vs baseline: 1.4246x; 1.4138x over previous
//
#include <hip/hip_runtime.h>
#include <hip/hip_bf16.h>
#include <cstdint>

// TGAT fused pipeline for MI355X — round 12: de-fenced, software-pipelined k3.
//   * atomics issued LAST each iteration; next tile's gathers issued before
//     them, so the vmcnt FIFO wait for gathers never drains the atomic queue
//   * atomic via __builtin_amdgcn_global_atomic_fadd_v2bf16 (compiler-modeled)
//     when available; else volatile asm WITHOUT "memory" clobber (nothing
//     in-kernel reads agg/den -> no aliasing hazard, no compiler barrier)
//   * den gets a private 64B line per node (was 16 nodes/line)
// Stages: k1 MFMA lin | k2 MFMA enc/proj | k3 edge | k4 epilogue (as r10)

#define FIN 172
#define INV_SQRT_C 0.25f

typedef _Float16 f16x8 __attribute__((ext_vector_type(8)));
typedef float f32x4 __attribute__((ext_vector_type(4)));
typedef short s16x2 __attribute__((ext_vector_type(2)));

__device__ __forceinline__ uint32_t cvt_pk_bf16(float lo, float hi) {
    uint32_t r;
    asm("v_cvt_pk_bf16_f32 %0, %1, %2" : "=v"(r) : "v"(lo), "v"(hi));
    return r;
}
__device__ __forceinline__ float bflo(uint32_t u) {
    union { uint32_t i; float f; } x; x.i = u << 16; return x.f;
}
__device__ __forceinline__ float bfhi(uint32_t u) {
    union { uint32_t i; float f; } x; x.i = u & 0xFFFF0000u; return x.f;
}

// Packed bf16 atomic add, fire-and-forget. Builtin path is modeled by the
// compiler's waitcnt pass; asm fallback is volatile but has NO "memory"
// clobber: agg/den are never read in-kernel, so no ordering is required and
// the compiler must not treat the atomic as a barrier against the gathers.
__device__ __forceinline__ void pk_atomic_add_bf16(void* addr, uint32_t data) {
#if __has_builtin(__builtin_amdgcn_global_atomic_fadd_v2bf16)
    typedef __attribute__((address_space(1))) s16x2* gp1;
    union { uint32_t u; s16x2 v; } c; c.u = data;
    __builtin_amdgcn_global_atomic_fadd_v2bf16((gp1)(uintptr_t)addr, c.v);
#else
    asm volatile("global_atomic_pk_add_bf16 %0, %1, off"
                 :: "v"((uint64_t)(uintptr_t)addr), "v"(data));
#endif
}

// ---------------------------------------------------------------------------
// k1 (MFMA): h1pre = x @ Wlin + blin. One wave per 16-node chunk, grid-stride.
// ---------------------------------------------------------------------------
__global__ __launch_bounds__(256) void k1_lin(
    const float* __restrict__ x, const float* __restrict__ Wlin,
    const float* __restrict__ blin, float* __restrict__ h1pre, int n)
{
    const int lane = threadIdx.x & 63;
    const int g = lane >> 4, m = lane & 15;

    f16x8 Bf[6][2];
    #pragma unroll
    for (int s = 0; s < 6; ++s) {
        #pragma unroll
        for (int i = 0; i < 8; ++i) {
            const int k = s * 32 + g * 8 + i;
            Bf[s][0][i] = (_Float16)((k < FIN) ? Wlin[k * 32 + m] : 0.f);
            Bf[s][1][i] = (_Float16)((k < FIN) ? Wlin[k * 32 + 16 + m] : 0.f);
        }
    }
    const float b0 = blin[m], b1 = blin[16 + m];

    const int wid = blockIdx.x * 4 + (threadIdx.x >> 6);
    const int nW  = gridDim.x * 4;
    const int nChunks = (n + 15) / 16;

    for (int c = wid; c < nChunks; c += nW) {
        const int row = c * 16 + m;
        const bool rv = row < n;
        const float* xr = x + (size_t)row * FIN;

        f32x4 acc0 = {0.f, 0.f, 0.f, 0.f};
        f32x4 acc1 = {0.f, 0.f, 0.f, 0.f};
        #pragma unroll
        for (int s = 0; s < 6; ++s) {
            f16x8 A;
            #pragma unroll
            for (int i = 0; i < 8; ++i) {
                const int k = s * 32 + g * 8 + i;
                A[i] = (_Float16)((rv && k < FIN) ? xr[k] : 0.f);
            }
            acc0 = __builtin_amdgcn_mfma_f32_16x16x32_f16(A, Bf[s][0], acc0, 0, 0, 0);
            acc1 = __builtin_amdgcn_mfma_f32_16x16x32_f16(A, Bf[s][1], acc1, 0, 0, 0);
        }
        #pragma unroll
        for (int r = 0; r < 4; ++r) {
            const int node = c * 16 + 4 * g + r;
            if (node < n) {
                h1pre[(size_t)node * 32 + m]      = acc0[r] + b0;
                h1pre[(size_t)node * 32 + 16 + m] = acc1[r] + b1;
            }
        }
    }
}

// ---------------------------------------------------------------------------
template <int K, int O>
__device__ __forceinline__ void matvecKO(const float* __restrict__ v,
                                         const float* __restrict__ W,
                                         const float* __restrict__ B,
                                         float* __restrict__ out)
{
    #pragma unroll
    for (int o4 = 0; o4 < O / 4; ++o4) {
        float a0 = B[o4 * 4 + 0], a1 = B[o4 * 4 + 1];
        float a2 = B[o4 * 4 + 2], a3 = B[o4 * 4 + 3];
        #pragma unroll
        for (int k = 0; k < K; ++k) {
            float4 wv = *reinterpret_cast<const float4*>(&W[k * O + o4 * 4]);
            float hv = v[k];
            a0 = fmaf(hv, wv.x, a0);
            a1 = fmaf(hv, wv.y, a1);
            a2 = fmaf(hv, wv.z, a2);
            a3 = fmaf(hv, wv.w, a3);
        }
        out[o4 * 4 + 0] = a0; out[o4 * 4 + 1] = a1;
        out[o4 * 4 + 2] = a2; out[o4 * 4 + 3] = a3;
    }
}

// ---------------------------------------------------------------------------
// k2: thread phase — encoders + gating -> v40 (LDS, f16);
//     wave phase  — comb + Q/K/V/skip as MFMAs (r10 verbatim).
// ---------------------------------------------------------------------------
__global__ __launch_bounds__(256) void k2_enc(
    const float* __restrict__ h1pre,
    const float* __restrict__ node_interval, const float* __restrict__ node_degree,
    const float* __restrict__ Wtf, const float* __restrict__ btf,
    const float* __restrict__ Wd,  const float* __restrict__ bd,
    const float* __restrict__ Wenc, const float* __restrict__ benc,
    const float* __restrict__ Wx,  const float* __restrict__ bx,
    const float* __restrict__ Wcomb, const float* __restrict__ bcomb,
    const float* __restrict__ Wq,  const float* __restrict__ bq,
    const float* __restrict__ Wk,  const float* __restrict__ bk,
    const float* __restrict__ Wv,  const float* __restrict__ bv,
    const float* __restrict__ Wskip, const float* __restrict__ bskip,
    uint32_t* __restrict__ q32, uint32_t* __restrict__ kv32,
    float* __restrict__ skipb, int n)
{
    __shared__ __align__(16) float sWenc[64], sWx[256];
    __shared__ float sWtf[8], sbtf[8], sWd[8], sbd[8], sbenc[8], sbx[8];
    __shared__ __align__(16) _Float16 v40s[256][72];
    __shared__ __align__(16) _Float16 h1s[256][40];

    const int t = threadIdx.x;
    if (t < 8) {
        sWtf[t] = Wtf[t]; sbtf[t] = btf[t];
        sWd[t]  = Wd[t];  sbd[t]  = bd[t];
        sbenc[t] = benc[t]; sbx[t] = bx[t];
    }
    if (t < 64) sWenc[t] = Wenc[t];
    if (t < 256) sWx[t] = Wx[t];

    const int nid = blockIdx.x * 256 + t;
    const bool active = nid < n;

    __syncthreads();

    if (active) {
        float h1p[32];
        const float2* hp = reinterpret_cast<const float2*>(h1pre + (size_t)nid * 32);
        #pragma unroll
        for (int i = 0; i < 16; ++i) {
            float2 v2 = hp[i];
            h1p[2 * i] = v2.x; h1p[2 * i + 1] = v2.y;
        }
        const float ti = node_interval[nid], dg = node_degree[nid];
        float tf[8], de[8];
        #pragma unroll
        for (int j = 0; j < 8; ++j) {
            tf[j] = fmaf(ti, sWtf[j], sbtf[j]);
            de[j] = fmaf(dg, sWd[j], sbd[j]);
        }
        float xp[8];
        matvecKO<32, 8>(h1p, sWx, sbx, xp);
        #pragma unroll
        for (int o = 0; o < 8; ++o) xp[o] = tanhf(xp[o]);

        float ep0[8], ep1[8];
        matvecKO<8, 8>(tf, sWenc, sbenc, ep0);
        matvecKO<8, 8>(de, sWenc, sbenc, ep1);
        float sc0 = 0.f, sc1 = 0.f;
        #pragma unroll
        for (int o = 0; o < 8; ++o) {
            sc0 = fmaf(tanhf(ep0[o]), xp[o], sc0);
            sc1 = fmaf(tanhf(ep1[o]), xp[o], sc1);
        }
        const float mm = fmaxf(sc0, sc1);
        const float e0 = __expf(sc0 - mm), e1 = __expf(sc1 - mm);
        const float inv = 1.f / (e0 + e1);
        const float s0 = e0 * inv, s1 = e1 * inv;

        #pragma unroll
        for (int i = 0; i < 32; ++i) v40s[t][i] = (_Float16)h1p[i];
        #pragma unroll
        for (int j = 0; j < 8; ++j)
            v40s[t][32 + j] = (_Float16)fmaf(s0, tf[j], s1 * de[j]);
    } else {
        #pragma unroll
        for (int i = 0; i < 40; ++i) v40s[t][i] = (_Float16)0.f;
    }
    #pragma unroll
    for (int i = 40; i < 64; ++i) v40s[t][i] = (_Float16)0.f;

    __syncthreads();

    const int lane = t & 63;
    const int g = lane >> 4, m = lane & 15;
    const int wv = t >> 6;
    const int node0 = blockIdx.x * 256;

    f16x8 Bc0[2], Bc1[2];
    #pragma unroll
    for (int s = 0; s < 2; ++s)
        #pragma unroll
        for (int i = 0; i < 8; ++i) {
            const int k = s * 32 + g * 8 + i;
            Bc0[s][i] = (_Float16)((k < 40) ? Wcomb[k * 32 + m] : 0.f);
            Bc1[s][i] = (_Float16)((k < 40) ? Wcomb[k * 32 + 16 + m] : 0.f);
        }
    const float bc0 = bcomb[m], bc1 = bcomb[16 + m];

    for (int c = wv; c < 16; c += 4) {
        f32x4 a0 = {0.f, 0.f, 0.f, 0.f};
        f32x4 a1 = {0.f, 0.f, 0.f, 0.f};
        #pragma unroll
        for (int s = 0; s < 2; ++s) {
            const f16x8 A = *reinterpret_cast<const f16x8*>(&v40s[c * 16 + m][s * 32 + g * 8]);
            a0 = __builtin_amdgcn_mfma_f32_16x16x32_f16(A, Bc0[s], a0, 0, 0, 0);
            a1 = __builtin_amdgcn_mfma_f32_16x16x32_f16(A, Bc1[s], a1, 0, 0, 0);
        }
        #pragma unroll
        for (int r = 0; r < 4; ++r) {
            const int nb = c * 16 + 4 * g + r;
            h1s[nb][m]      = (_Float16)(a0[r] + bc0);
            h1s[nb][16 + m] = (_Float16)(a1[r] + bc1);
        }
    }
    __syncthreads();

    f16x8 Bq0, Bq1, Bk0, Bk1, Bv0, Bv1, Bs0, Bs1;
    #pragma unroll
    for (int i = 0; i < 8; ++i) {
        const int k = g * 8 + i;
        Bq0[i] = (_Float16)Wq[k * 32 + m];     Bq1[i] = (_Float16)Wq[k * 32 + 16 + m];
        Bk0[i] = (_Float16)Wk[k * 32 + m];     Bk1[i] = (_Float16)Wk[k * 32 + 16 + m];
        Bv0[i] = (_Float16)Wv[k * 32 + m];     Bv1[i] = (_Float16)Wv[k * 32 + 16 + m];
        Bs0[i] = (_Float16)Wskip[k * 32 + m];  Bs1[i] = (_Float16)Wskip[k * 32 + 16 + m];
    }
    const float bq0 = bq[m], bq1 = bq[16 + m];
    const float bk0 = bk[m], bk1 = bk[16 + m];
    const float bv0 = bv[m], bv1 = bv[16 + m];
    const float bs0 = bskip[m], bs1 = bskip[16 + m];

    for (int c = wv; c < 16; c += 4) {
        const f16x8 A = *reinterpret_cast<const f16x8*>(&h1s[c * 16 + m][g * 8]);

        f32x4 aq0 = {0.f,0.f,0.f,0.f}, aq1 = {0.f,0.f,0.f,0.f};
        f32x4 ak0 = {0.f,0.f,0.f,0.f}, ak1 = {0.f,0.f,0.f,0.f};
        f32x4 av0 = {0.f,0.f,0.f,0.f}, av1 = {0.f,0.f,0.f,0.f};
        f32x4 as0 = {0.f,0.f,0.f,0.f}, as1 = {0.f,0.f,0.f,0.f};
        aq0 = __builtin_amdgcn_mfma_f32_16x16x32_f16(A, Bq0, aq0, 0, 0, 0);
        aq1 = __builtin_amdgcn_mfma_f32_16x16x32_f16(A, Bq1, aq1, 0, 0, 0);
        ak0 = __builtin_amdgcn_mfma_f32_16x16x32_f16(A, Bk0, ak0, 0, 0, 0);
        ak1 = __builtin_amdgcn_mfma_f32_16x16x32_f16(A, Bk1, ak1, 0, 0, 0);
        av0 = __builtin_amdgcn_mfma_f32_16x16x32_f16(A, Bv0, av0, 0, 0, 0);
        av1 = __builtin_amdgcn_mfma_f32_16x16x32_f16(A, Bv1, av1, 0, 0, 0);
        as0 = __builtin_amdgcn_mfma_f32_16x16x32_f16(A, Bs0, as0, 0, 0, 0);
        as1 = __builtin_amdgcn_mfma_f32_16x16x32_f16(A, Bs1, as1, 0, 0, 0);

        #pragma unroll
        for (int r = 0; r < 4; ++r) {
            const int node = node0 + c * 16 + 4 * g + r;
            if (node < n) {
                q32[(size_t)node * 16 + m] =
                    cvt_pk_bf16(aq0[r] + bq0, aq1[r] + bq1);
                uint2 kvd;
                kvd.x = cvt_pk_bf16(ak0[r] + bk0, ak1[r] + bk1);
                kvd.y = cvt_pk_bf16(av0[r] + bv0, av1[r] + bv1);
                *reinterpret_cast<uint2*>(kv32 + (size_t)node * 32 + 2 * m) = kvd;
                skipb[(size_t)node * 32 + m]      = as0[r] + bs0;
                skipb[(size_t)node * 32 + 16 + m] = as1[r] + bs1;
            }
        }
    }
}

// ---------------------------------------------------------------------------
// k3: edge kernel, pipelined so atomics never sit on a wait path.
// Per iteration (tile t):
//   1. compute tile t  — waits only on gathers(t), which were issued BEFORE
//      atomics(t-1) last iteration (vmcnt FIFO: no atomic drain)
//   2. issue gathers(t+1) + stage-1(t+2), overwriting the gather state
//   3. issue atomics(t) LAST, from saved {dst, data} registers
// den rows are private 64B lines (den[n][32] shorts, slots 0..1 used).
// ---------------------------------------------------------------------------
__global__ __launch_bounds__(256) void k3_edge(
    const int* __restrict__ ei, const float* __restrict__ node_time,
    const float* __restrict__ edge_time,
    const uint32_t* __restrict__ qp, const uint32_t* __restrict__ kvp,
    const float* __restrict__ Wt, const float* __restrict__ bt,
    const float* __restrict__ We, const float* __restrict__ be,
    unsigned short* __restrict__ agg, unsigned short* __restrict__ den,
    int numE, int nTiles)
{
    const int lane = threadIdx.x & 63;
    const int g = lane >> 4;
    const int m = lane & 15;

    float wtr[8], btr[8];
    f16x8 B0, B1;
    #pragma unroll
    for (int i = 0; i < 8; ++i) {
        const int k = g * 8 + i;
        wtr[i] = Wt[k];
        btr[i] = bt[k];
        B0[i] = (_Float16)We[k * 32 + m];
        B1[i] = (_Float16)We[k * 32 + 16 + m];
    }
    const float be0 = be[m], be1 = be[16 + m];

    const int wid = blockIdx.x * (blockDim.x >> 6) + (threadIdx.x >> 6);
    const int nW  = gridDim.x * (blockDim.x >> 6);

    int tile = wid;
    if (tile >= nTiles) return;

    // ---------------- prologue ----------------
    // stage-1(t0)
    int srcS = 0, dstS = 0; float etS = 0.f;
    {
        const int eA = tile * 16 + m;
        if (eA < numE) { srcS = ei[eA]; dstS = ei[numE + eA]; etS = edge_time[eA]; }
    }
    // gathers(t0)
    float ntC = node_time[srcS];
    float etC = etS;
    int dstrC[4]; uint32_t qwC[4]; uint2 kvwC[4];
    #pragma unroll
    for (int r = 0; r < 4; ++r) {
        const int j = g * 4 + r;
        const int s_ = __shfl(srcS, j);
        dstrC[r] = __shfl(dstS, j);
        qwC[r]  = qp[(size_t)dstrC[r] * 16 + m];
        kvwC[r] = *reinterpret_cast<const uint2*>(kvp + (size_t)s_ * 32 + 2 * m);
    }
    // stage-1(t1)
    int ntile = tile + nW;
    srcS = 0; dstS = 0; etS = 0.f;
    if (ntile < nTiles) {
        const int eA = ntile * 16 + m;
        if (eA < numE) { srcS = ei[eA]; dstS = ei[numE + eA]; etS = edge_time[eA]; }
    }

    while (true) {
        // ---- 1. compute tile t (consumes gather state) ----
        const float rel = ntC - etC;
        f16x8 A;
        #pragma unroll
        for (int i = 0; i < 8; ++i)
            A[i] = (_Float16)__cosf(fmaf(rel, wtr[i], btr[i]));

        f32x4 acc0 = {0.f, 0.f, 0.f, 0.f};
        f32x4 acc1 = {0.f, 0.f, 0.f, 0.f};
        acc0 = __builtin_amdgcn_mfma_f32_16x16x32_f16(A, B0, acc0, 0, 0, 0);
        acc1 = __builtin_amdgcn_mfma_f32_16x16x32_f16(A, B1, acc1, 0, 0, 0);

        const int e0 = tile * 16;
        uint32_t outD[4], denD[4];
        int outDst[4];
        bool outV[4];
        #pragma unroll
        for (int r = 0; r < 4; ++r) {
            outV[r]   = (e0 + g * 4 + r) < numE;
            outDst[r] = dstrC[r];

            const float ef0 = acc0[r] + be0;
            const float ef1 = acc1[r] + be1;
            const uint32_t uq = qwC[r], uk = kvwC[r].x, uv = kvwC[r].y;

            float p0 = bflo(uq) * (bflo(uk) + ef0);
            float p1 = bfhi(uq) * (bfhi(uk) + ef1);
            #pragma unroll
            for (int s = 1; s < 16; s <<= 1) {
                p0 += __shfl_xor(p0, s);
                p1 += __shfl_xor(p1, s);
            }
            const float w0 = __expf(p0 * INV_SQRT_C);
            const float w1 = __expf(p1 * INV_SQRT_C);

            const float t0 = w0 * (bflo(uv) + ef0);
            const float t1 = w1 * (bfhi(uv) + ef1);
            const float x0 = __shfl_xor(t0, 1);
            const float x1 = __shfl_xor(t1, 1);
            outD[r] = (m & 1) ? cvt_pk_bf16(x1, t1) : cvt_pk_bf16(t0, x0);
            denD[r] = cvt_pk_bf16(w0, w1);
        }

        // ---- 2. issue gathers(t+1) + stage-1(t+2) BEFORE the atomics ----
        const bool haveN = ntile < nTiles;
        if (haveN) {
            ntC = node_time[srcS];
            etC = etS;
            #pragma unroll
            for (int r = 0; r < 4; ++r) {
                const int j = g * 4 + r;
                const int s_ = __shfl(srcS, j);
                dstrC[r] = __shfl(dstS, j);
                qwC[r]  = qp[(size_t)dstrC[r] * 16 + m];
                kvwC[r] = *reinterpret_cast<const uint2*>(kvp + (size_t)s_ * 32 + 2 * m);
            }
            const int n2 = ntile + nW;
            srcS = 0; dstS = 0; etS = 0.f;
            if (n2 < nTiles) {
                const int eA = n2 * 16 + m;
                if (eA < numE) { srcS = ei[eA]; dstS = ei[numE + eA]; etS = edge_time[eA]; }
            }
        }

        // ---- 3. atomics for tile t (issued last; never waited on) ----
        const int choff = (m & 1) ? (15 + m) : m;
        #pragma unroll
        for (int r = 0; r < 4; ++r) {
            if (outV[r]) {
                pk_atomic_add_bf16(agg + (size_t)outDst[r] * 32 + choff, outD[r]);
                if (m == 0)
                    pk_atomic_add_bf16(den + (size_t)outDst[r] * 32, denD[r]);
            }
        }

        if (!haveN) break;
        tile = ntile; ntile += nW;
    }
}

// ---------------------------------------------------------------------------
// k4: h2 = agg(bf16)/den(bf16) + skip; out = log_softmax(h2 @ Wout + bout).
// den stride is now 32 shorts (private line per node).
// ---------------------------------------------------------------------------
__global__ __launch_bounds__(256) void k4_out(
    const unsigned short* __restrict__ agg, const unsigned short* __restrict__ den,
    const float* __restrict__ skipb,
    const float* __restrict__ Wout, const float* __restrict__ bout,
    float* __restrict__ out, int n)
{
    __shared__ float sW[64];
    __shared__ float sb[2];
    const int t = threadIdx.x;
    if (t < 64) sW[t] = Wout[t];
    if (t < 2) sb[t] = bout[t];
    __syncthreads();

    const int nid = blockIdx.x * 256 + t;
    if (nid >= n) return;

    const uint32_t ud = reinterpret_cast<const uint32_t*>(den)[(size_t)nid * 16];
    const float inv0 = 1.f / (bflo(ud) + 1e-16f);
    const float inv1 = 1.f / (bfhi(ud) + 1e-16f);
    const uint32_t* ag = reinterpret_cast<const uint32_t*>(agg) + (size_t)nid * 16;
    const float*    sk = skipb + (size_t)nid * 32;

    float o0 = sb[0], o1 = sb[1];
    #pragma unroll
    for (int p = 0; p < 16; ++p) {
        const uint32_t u = ag[p];
        const float iv = (p < 8) ? inv0 : inv1;
        const float hLo = fmaf(bflo(u), iv, sk[2 * p]);
        const float hHi = fmaf(bfhi(u), iv, sk[2 * p + 1]);
        o0 = fmaf(hLo, sW[(2 * p) * 2],     o0);
        o1 = fmaf(hLo, sW[(2 * p) * 2 + 1], o1);
        o0 = fmaf(hHi, sW[(2 * p + 1) * 2],     o0);
        o1 = fmaf(hHi, sW[(2 * p + 1) * 2 + 1], o1);
    }
    const float mm = fmaxf(o0, o1);
    const float lse = mm + __logf(__expf(o0 - mm) + __expf(o1 - mm));
    out[(size_t)nid * 2 + 0] = o0 - lse;
    out[(size_t)nid * 2 + 1] = o1 - lse;
}

// ---------------------------------------------------------------------------
extern "C" void kernel_launch(void* const* d_in, const int* in_sizes, int n_in,
                              void* d_out, int out_size, void* d_ws, size_t ws_size,
                              hipStream_t stream)
{
    const float* x             = (const float*)d_in[0];
    const int*   ei            = (const int*)  d_in[1];
    const float* node_time     = (const float*)d_in[2];
    const float* edge_time     = (const float*)d_in[3];
    const float* node_interval = (const float*)d_in[4];
    const float* node_degree   = (const float*)d_in[5];
    const float* Wt    = (const float*)d_in[6];  const float* bt    = (const float*)d_in[7];
    const float* Wd    = (const float*)d_in[8];  const float* bd    = (const float*)d_in[9];
    const float* Wtf   = (const float*)d_in[10]; const float* btf   = (const float*)d_in[11];
    const float* Wenc  = (const float*)d_in[12]; const float* benc  = (const float*)d_in[13];
    const float* Wx    = (const float*)d_in[14]; const float* bx    = (const float*)d_in[15];
    const float* Wlin  = (const float*)d_in[16]; const float* blin  = (const float*)d_in[17];
    const float* Wcomb = (const float*)d_in[18]; const float* bcomb = (const float*)d_in[19];
    const float* Wq    = (const float*)d_in[20]; const float* bq    = (const float*)d_in[21];
    const float* Wk    = (const float*)d_in[22]; const float* bk    = (const float*)d_in[23];
    const float* Wv    = (const float*)d_in[24]; const float* bv    = (const float*)d_in[25];
    const float* We    = (const float*)d_in[26]; const float* be    = (const float*)d_in[27];
    const float* Wskip = (const float*)d_in[28]; const float* bskip = (const float*)d_in[29];
    const float* Wout  = (const float*)d_in[30]; const float* bout  = (const float*)d_in[31];

    const int n    = in_sizes[2];   // node_time: [N]
    const int numE = in_sizes[3];   // edge_time: [E,1]

    // ---- workspace carve (bytes) ----
    char* base = (char*)d_ws;
    uint32_t* q32  = (uint32_t*)base; base += (size_t)n * 16 * 4;   // q pairs
    uint32_t* kv32 = (uint32_t*)base; base += (size_t)n * 32 * 4;   // kv quads
    float* skipb = (float*)base; base += (size_t)n * 32 * 4;
    float* h1pre = (float*)base; base += (size_t)n * 32 * 4;
    unsigned short* agg = (unsigned short*)base; base += (size_t)n * 32 * 2;
    unsigned short* den = (unsigned short*)base; base += (size_t)n * 32 * 2;

    // zero the atomic accumulators (agg + den rows, contiguous: 128 B/node)
    hipMemsetAsync(agg, 0, (size_t)n * 128, stream);

    k1_lin<<<512, 256, 0, stream>>>(x, Wlin, blin, h1pre, n);

    k2_enc<<<(n + 255) / 256, 256, 0, stream>>>(
        h1pre, node_interval, node_degree,
        Wtf, btf, Wd, bd, Wenc, benc, Wx, bx, Wcomb, bcomb,
        Wq, bq, Wk, bk, Wv, bv, Wskip, bskip,
        q32, kv32, skipb, n);

    const int nTiles = (numE + 15) / 16;
    k3_edge<<<4096, 256, 0, stream>>>(
        ei, node_time, edge_time, q32, kv32,
        Wt, bt, We, be, agg, den, numE, nTiles);

    k4_out<<<(n + 255) / 256, 256, 0, stream>>>(
        agg, den, skipb, Wout, bout, (float*)d_out, n);
}